// Round 9
// baseline (191.084 us; speedup 1.0000x reference)
//
#include <hip/hip_runtime.h>
#include <stdint.h>

#define D 128
#define LIST_CAP 256

// LDS floats: P[16384] | U[8*128] | R[8*128] | part[8*128] | list[256] | El[8] | cnt[1]
#define SMEM_FLOATS (16384 + 1024 + 1024 + 1024 + LIST_CAP + 8 + 1)
#define SMEM_BYTES (SMEM_FLOATS * 4)

__global__ __launch_bounds__(512, 4) void transr_fused(
    const float* __restrict__ head,
    const float* __restrict__ tail,
    const float* __restrict__ edge,
    const float* __restrict__ proj,
    const int* __restrict__ idx,
    float* __restrict__ out,
    int B)
{
    const int rel = blockIdx.x;
    const int tid = threadIdx.x;

    extern __shared__ float sm[];
    float* Pl   = sm;                       // 16384, XOR-swizzled quads
    float* Ul   = sm + 16384;               // 8 x 128
    float* Rl   = sm + 17408;               // 8 x 128
    float* part = sm + 18432;               // 8 x 128 (cross-wave accumulator)
    int*   list = (int*)(sm + 19456);       // 256
    int*   El   = (int*)(sm + 19456 + LIST_CAP); // 8
    int*   cnt  = El + 8;                   // 1

    if (tid == 0) *cnt = 0;
    part[tid] = 0.f;
    part[tid + 512] = 0.f;

    // ---- stage P via global_load_lds: linear LDS dest, pre-swizzled global src ----
    const float* __restrict__ Pg = proj + (size_t)rel * (D * D);
    #pragma unroll
    for (int i = 0; i < 8; ++i) {
        const int f   = i * 512 + tid;      // quad index 0..4095
        const int row = f >> 5;
        const int q   = f & 31;
        const float* src = Pg + row * D + 4 * (q ^ (row & 31));
        float* dst = Pl + 4 * f;
        __builtin_amdgcn_global_load_lds(
            (const __attribute__((address_space(1))) uint32_t*)src,
            (__attribute__((address_space(3))) uint32_t*)dst,
            16, 0, 0);
    }

    __syncthreads();   // cnt/part zeroed visible (P loads still in flight)

    // ---- self-bucketing: scan idx for this relation (overlaps P loads) ----
    const int4* __restrict__ idx4 = reinterpret_cast<const int4*>(idx);
    const int nv = B >> 2;
    for (int f = tid; f < nv; f += 512) {
        const int4 v = idx4[f];
        if (v.x == rel) { int p = atomicAdd(cnt, 1); if (p < LIST_CAP) list[p] = 4 * f + 0; }
        if (v.y == rel) { int p = atomicAdd(cnt, 1); if (p < LIST_CAP) list[p] = 4 * f + 1; }
        if (v.z == rel) { int p = atomicAdd(cnt, 1); if (p < LIST_CAP) list[p] = 4 * f + 2; }
        if (v.w == rel) { int p = atomicAdd(cnt, 1); if (p < LIST_CAP) list[p] = 4 * f + 3; }
    }
    __syncthreads();   // list ready AND vmcnt(0): P fully in LDS
    const int n = min(*cnt, LIST_CAP);
    if (n == 0) return;

    const int w  = tid >> 6;    // wave 0..7
    const int wl = tid & 63;
    const int cq = w & 3;       // col quarter: cols [32cq, 32cq+32)
    const int eh = w >> 2;      // element half: elems [4eh, 4eh+4)
    const int rowA = wl;
    const int rowB = wl + 64;
    const int sx = wl & 31;     // swizzle key (== rowA&31 == rowB&31)

    // ---- load this lane's P tile into registers ONCE (2 rows x 32 cols) ----
    float4 pA[8], pB[8];
    #pragma unroll
    for (int k = 0; k < 8; ++k) {
        const int ql = 8 * cq + k;           // logical quad within row
        pA[k] = *reinterpret_cast<const float4*>(Pl + rowA * D + 4 * (ql ^ sx));
        pB[k] = *reinterpret_cast<const float4*>(Pl + rowB * D + 4 * (ql ^ sx));
    }

    const int nchunk = (n + 7) >> 3;
    for (int ch = 0; ch < nchunk; ++ch) {
        // ---- Phase A: wave w normalizes element ch*8+w; u = h/|h| - t/|t| ----
        const int e = ch * 8 + w;
        int b = -1;
        float2 u2 = make_float2(0.f, 0.f);
        float2 r2 = make_float2(0.f, 0.f);
        if (e < n) {
            b = list[e];
            const float2 h2 = *reinterpret_cast<const float2*>(head + (size_t)b * D + 2 * wl);
            const float2 t2 = *reinterpret_cast<const float2*>(tail + (size_t)b * D + 2 * wl);
            r2 = *reinterpret_cast<const float2*>(edge + (size_t)b * D + 2 * wl);
            float hs = h2.x * h2.x + h2.y * h2.y;
            float ts = t2.x * t2.x + t2.y * t2.y;
            #pragma unroll
            for (int m = 1; m < 64; m <<= 1) {
                hs += __shfl_xor(hs, m);
                ts += __shfl_xor(ts, m);
            }
            const float hn = fmaxf(sqrtf(hs), 1e-12f);
            const float tn = fmaxf(sqrtf(ts), 1e-12f);
            u2.x = h2.x / hn - t2.x / tn;
            u2.y = h2.y / hn - t2.y / tn;
        }
        *reinterpret_cast<float2*>(Ul + w * D + 2 * wl) = u2;
        *reinterpret_cast<float2*>(Rl + w * D + 2 * wl) = r2;
        if (wl == 0) El[w] = b;
        __syncthreads();

        // ---- Phase B: 4 elements x 2 rows x 32 cols, all from registers + broadcast u ----
        #pragma unroll
        for (int j = 0; j < 4; ++j) {
            const int e2 = eh * 4 + j;
            const float* Ue = Ul + e2 * D + 32 * cq;   // wave-uniform -> broadcast reads
            float a0 = 0.f, a1 = 0.f;
            #pragma unroll
            for (int k = 0; k < 8; ++k) {
                const float4 u = *reinterpret_cast<const float4*>(Ue + 4 * k);
                a0 = fmaf(pA[k].x, u.x, a0); a0 = fmaf(pA[k].y, u.y, a0);
                a0 = fmaf(pA[k].z, u.z, a0); a0 = fmaf(pA[k].w, u.w, a0);
                a1 = fmaf(pB[k].x, u.x, a1); a1 = fmaf(pB[k].y, u.y, a1);
                a1 = fmaf(pB[k].z, u.z, a1); a1 = fmaf(pB[k].w, u.w, a1);
            }
            atomicAdd(&part[e2 * D + rowA], a0);
            atomicAdd(&part[e2 * D + rowB], a1);
        }
        __syncthreads();

        // ---- final: wave w scores element w; re-zero part in place ----
        {
            const float p0 = part[w * D + wl];
            const float p1 = part[w * D + wl + 64];
            part[w * D + wl] = 0.f;
            part[w * D + wl + 64] = 0.f;
            const float d0 = p0 + Rl[w * D + wl];
            const float d1 = p1 + Rl[w * D + wl + 64];
            float s = fmaf(d0, d0, d1 * d1);
            #pragma unroll
            for (int m = 1; m < 64; m <<= 1) s += __shfl_xor(s, m);
            if (wl == 0) {
                const int bb = El[w];
                if (bb >= 0) out[bb] = -s;
            }
        }
        __syncthreads();   // part re-zeroed + U/R free before next chunk
    }
}

extern "C" void kernel_launch(void* const* d_in, const int* in_sizes, int n_in,
                              void* d_out, int out_size, void* d_ws, size_t ws_size,
                              hipStream_t stream) {
    const float* head = (const float*)d_in[0];
    const float* tail = (const float*)d_in[1];
    const float* edge = (const float*)d_in[2];
    const float* proj = (const float*)d_in[3];
    const int*   idx  = (const int*)d_in[4];
    float* out = (float*)d_out;

    const int B    = in_sizes[0] / D;          // 16384
    const int nrel = in_sizes[3] / (D * D);    // 1000

    hipFuncSetAttribute(reinterpret_cast<const void*>(transr_fused),
                        hipFuncAttributeMaxDynamicSharedMemorySize, SMEM_BYTES);
    transr_fused<<<nrel, 512, SMEM_BYTES, stream>>>(head, tail, edge, proj,
                                                    idx, out, B);
}

// Round 10
// 154.172 us; speedup vs baseline: 1.2394x; 1.2394x over previous
//
#include <hip/hip_runtime.h>
#include <stdint.h>

#define D 128
#define LIST_CAP 256

__global__ __launch_bounds__(512, 6) void transr_fused(
    const float* __restrict__ head,
    const float* __restrict__ tail,
    const float* __restrict__ edge,
    const float* __restrict__ proj,
    const int* __restrict__ idx,
    float* __restrict__ out,
    int B)
{
    const int rel = blockIdx.x;
    const int tid = threadIdx.x;

    __shared__ float Ul[8 * D];      // u = h/|h| - t/|t| per chunk element
    __shared__ float Rl[8 * D];      // edge embeddings per chunk element
    __shared__ float part[64];       // [elem][wave] partial sums
    __shared__ int   list[LIST_CAP];
    __shared__ int   El[8];
    __shared__ int   cnt;

    if (tid == 0) cnt = 0;

    const int w  = tid >> 6;         // wave 0..7
    const int wl = tid & 63;
    const int r  = 16 * w + (wl >> 2);   // row this lane owns
    const int cq = wl & 3;               // col quarter [32cq, 32cq+32)

    // ---- P tile straight into registers: 1 row x 32 cols per lane (32 VGPRs) ----
    const float* __restrict__ Pg = proj + (size_t)rel * (D * D) + (size_t)r * D + 32 * cq;
    float4 pT[8];
    #pragma unroll
    for (int k = 0; k < 8; ++k)
        pT[k] = *reinterpret_cast<const float4*>(Pg + 4 * k);

    __syncthreads();   // cnt=0 visible before atomics

    // ---- self-bucketing: scan idx for this relation ----
    const int4* __restrict__ idx4 = reinterpret_cast<const int4*>(idx);
    const int nv = B >> 2;
    for (int f = tid; f < nv; f += 512) {
        const int4 v = idx4[f];
        if (v.x == rel) { int p = atomicAdd(&cnt, 1); if (p < LIST_CAP) list[p] = 4 * f + 0; }
        if (v.y == rel) { int p = atomicAdd(&cnt, 1); if (p < LIST_CAP) list[p] = 4 * f + 1; }
        if (v.z == rel) { int p = atomicAdd(&cnt, 1); if (p < LIST_CAP) list[p] = 4 * f + 2; }
        if (v.w == rel) { int p = atomicAdd(&cnt, 1); if (p < LIST_CAP) list[p] = 4 * f + 3; }
    }
    __syncthreads();
    const int n = min(cnt, LIST_CAP);
    if (n == 0) return;

    const int nchunk = (n + 7) >> 3;
    for (int ch = 0; ch < nchunk; ++ch) {
        // ---- Phase A: wave w normalizes element ch*8+w; u = h/|h| - t/|t| ----
        const int e = ch * 8 + w;
        int b = -1;
        float2 u2 = make_float2(0.f, 0.f);
        float2 r2 = make_float2(0.f, 0.f);
        if (e < n) {                                   // wave-uniform branch
            b = list[e];
            const float2 h2 = *reinterpret_cast<const float2*>(head + (size_t)b * D + 2 * wl);
            const float2 t2 = *reinterpret_cast<const float2*>(tail + (size_t)b * D + 2 * wl);
            r2 = *reinterpret_cast<const float2*>(edge + (size_t)b * D + 2 * wl);
            float hs = h2.x * h2.x + h2.y * h2.y;
            float ts = t2.x * t2.x + t2.y * t2.y;
            #pragma unroll
            for (int m = 1; m < 64; m <<= 1) {
                hs += __shfl_xor(hs, m);
                ts += __shfl_xor(ts, m);
            }
            const float hn = fmaxf(sqrtf(hs), 1e-12f);
            const float tn = fmaxf(sqrtf(ts), 1e-12f);
            u2.x = h2.x / hn - t2.x / tn;
            u2.y = h2.y / hn - t2.y / tn;
        }
        *reinterpret_cast<float2*>(Ul + w * D + 2 * wl) = u2;
        *reinterpret_cast<float2*>(Rl + w * D + 2 * wl) = r2;
        if (wl == 0) El[w] = b;
        __syncthreads();

        // ---- Phase B: 8 elements vs register tile ----
        #pragma unroll
        for (int e2 = 0; e2 < 8; ++e2) {
            const float* Ue = Ul + e2 * D + 32 * cq;   // 4 distinct addrs/wave: multicast
            float a = 0.f;
            #pragma unroll
            for (int k = 0; k < 8; ++k) {
                const float4 u = *reinterpret_cast<const float4*>(Ue + 4 * k);
                a = fmaf(pT[k].x, u.x, a); a = fmaf(pT[k].y, u.y, a);
                a = fmaf(pT[k].z, u.z, a); a = fmaf(pT[k].w, u.w, a);
            }
            // full row dot: reduce over the 4 lanes of this row group
            a += __shfl_xor(a, 1);
            a += __shfl_xor(a, 2);
            const float dfr = a + Rl[e2 * D + r];
            float s = (cq == 0) ? dfr * dfr : 0.f;     // one contributor per row
            s += __shfl_xor(s, 4);
            s += __shfl_xor(s, 8);
            s += __shfl_xor(s, 16);
            s += __shfl_xor(s, 32);
            if (wl == 0) part[e2 * 8 + w] = s;         // wave w's 16-row partial
        }
        __syncthreads();

        // ---- final: wave w sums element w's 8 wave-partials, writes score ----
        {
            float v = (wl < 8) ? part[w * 8 + wl] : 0.f;
            v += __shfl_xor(v, 1);
            v += __shfl_xor(v, 2);
            v += __shfl_xor(v, 4);
            if (wl == 0) {
                const int bb = El[w];
                if (bb >= 0) out[bb] = -v;
            }
        }
        __syncthreads();   // Ul/Rl/El/part free before next chunk
    }
}

extern "C" void kernel_launch(void* const* d_in, const int* in_sizes, int n_in,
                              void* d_out, int out_size, void* d_ws, size_t ws_size,
                              hipStream_t stream) {
    const float* head = (const float*)d_in[0];
    const float* tail = (const float*)d_in[1];
    const float* edge = (const float*)d_in[2];
    const float* proj = (const float*)d_in[3];
    const int*   idx  = (const int*)d_in[4];
    float* out = (float*)d_out;

    const int B    = in_sizes[0] / D;          // 16384
    const int nrel = in_sizes[3] / (D * D);    // 1000

    transr_fused<<<nrel, 512, 0, stream>>>(head, tail, edge, proj, idx, out, B);
}

// Round 11
// 141.693 us; speedup vs baseline: 1.3486x; 1.0881x over previous
//
#include <hip/hip_runtime.h>
#include <stdint.h>

#define D 128
#define LIST_CAP 256
#define CHUNK 16

__global__ __launch_bounds__(512, 4) void transr_fused(
    const float* __restrict__ head,
    const float* __restrict__ tail,
    const float* __restrict__ edge,
    const float* __restrict__ proj,
    const int* __restrict__ idx,
    float* __restrict__ out,
    int B)
{
    const int rel = blockIdx.x;
    const int tid = threadIdx.x;

    __shared__ float Ul[CHUNK][D];        // u = h/|h| - t/|t|
    __shared__ float Rl[CHUNK][D];        // edge embeddings
    __shared__ float part4[4][CHUNK][D];  // per-col-quarter partials (overwritten each chunk)
    __shared__ int   list[LIST_CAP];
    __shared__ int   El[CHUNK];
    __shared__ int   cnt;

    if (tid == 0) cnt = 0;

    const int w  = tid >> 6;   // wave 0..7
    const int wl = tid & 63;
    const int cq = w & 3;      // col quarter [32cq, 32cq+32)
    const int eh = w >> 2;     // element half: slots [8eh, 8eh+8)

    // ---- P tile: rows wl, wl+64  x  cols [32cq,32cq+32) -> 16 float4 = 64 VGPR ----
    const float* __restrict__ Pg  = proj + (size_t)rel * (D * D);
    const float* __restrict__ PgA = Pg + (size_t)wl * D + 32 * cq;
    const float* __restrict__ PgB = Pg + (size_t)(wl + 64) * D + 32 * cq;
    float4 pA[8], pB[8];
    #pragma unroll
    for (int k = 0; k < 8; ++k) {
        pA[k] = *reinterpret_cast<const float4*>(PgA + 4 * k);
        pB[k] = *reinterpret_cast<const float4*>(PgB + 4 * k);
    }

    __syncthreads();   // cnt=0 visible

    // ---- self-bucketing: scan idx for this relation (overlaps P loads) ----
    const int4* __restrict__ idx4 = reinterpret_cast<const int4*>(idx);
    const int nv = B >> 2;
    for (int f = tid; f < nv; f += 512) {
        const int4 v = idx4[f];
        if (v.x == rel) { int p = atomicAdd(&cnt, 1); if (p < LIST_CAP) list[p] = 4 * f + 0; }
        if (v.y == rel) { int p = atomicAdd(&cnt, 1); if (p < LIST_CAP) list[p] = 4 * f + 1; }
        if (v.z == rel) { int p = atomicAdd(&cnt, 1); if (p < LIST_CAP) list[p] = 4 * f + 2; }
        if (v.w == rel) { int p = atomicAdd(&cnt, 1); if (p < LIST_CAP) list[p] = 4 * f + 3; }
    }
    __syncthreads();
    const int n = min(cnt, LIST_CAP);
    if (n == 0) return;

    // ---- pin P tile in VGPRs: values become opaque, compiler CANNOT re-load ----
    #pragma unroll
    for (int k = 0; k < 8; ++k) {
        asm volatile("" : "+v"(pA[k].x), "+v"(pA[k].y), "+v"(pA[k].z), "+v"(pA[k].w));
        asm volatile("" : "+v"(pB[k].x), "+v"(pB[k].y), "+v"(pB[k].z), "+v"(pB[k].w));
    }

    const int nchunk = (n + CHUNK - 1) / CHUNK;
    for (int ch = 0; ch < nchunk; ++ch) {
        // ---- Phase A: wave w normalizes chunk slots 2w, 2w+1 (concurrent loads) ----
        const int eA = ch * CHUNK + 2 * w;
        const int eB = eA + 1;
        const int bA = (eA < n) ? list[eA] : -1;
        const int bB = (eB < n) ? list[eB] : -1;
        float2 hA = make_float2(0.f, 0.f), tA = hA, rA = hA;
        float2 hB = hA, tB = hA, rB = hA;
        if (bA >= 0) {    // wave-uniform branch
            hA = *reinterpret_cast<const float2*>(head + (size_t)bA * D + 2 * wl);
            tA = *reinterpret_cast<const float2*>(tail + (size_t)bA * D + 2 * wl);
            rA = *reinterpret_cast<const float2*>(edge + (size_t)bA * D + 2 * wl);
        }
        if (bB >= 0) {
            hB = *reinterpret_cast<const float2*>(head + (size_t)bB * D + 2 * wl);
            tB = *reinterpret_cast<const float2*>(tail + (size_t)bB * D + 2 * wl);
            rB = *reinterpret_cast<const float2*>(edge + (size_t)bB * D + 2 * wl);
        }
        float hsA = hA.x * hA.x + hA.y * hA.y, tsA = tA.x * tA.x + tA.y * tA.y;
        float hsB = hB.x * hB.x + hB.y * hB.y, tsB = tB.x * tB.x + tB.y * tB.y;
        #pragma unroll
        for (int m = 1; m < 64; m <<= 1) {
            hsA += __shfl_xor(hsA, m); tsA += __shfl_xor(tsA, m);
            hsB += __shfl_xor(hsB, m); tsB += __shfl_xor(tsB, m);
        }
        const float hnA = fmaxf(sqrtf(hsA), 1e-12f), tnA = fmaxf(sqrtf(tsA), 1e-12f);
        const float hnB = fmaxf(sqrtf(hsB), 1e-12f), tnB = fmaxf(sqrtf(tsB), 1e-12f);
        float2 uA, uB;
        uA.x = hA.x / hnA - tA.x / tnA;  uA.y = hA.y / hnA - tA.y / tnA;
        uB.x = hB.x / hnB - tB.x / tnB;  uB.y = hB.y / hnB - tB.y / tnB;
        *reinterpret_cast<float2*>(&Ul[2 * w    ][2 * wl]) = uA;
        *reinterpret_cast<float2*>(&Ul[2 * w + 1][2 * wl]) = uB;
        *reinterpret_cast<float2*>(&Rl[2 * w    ][2 * wl]) = rA;
        *reinterpret_cast<float2*>(&Rl[2 * w + 1][2 * wl]) = rB;
        if (wl == 0) { El[2 * w] = bA; El[2 * w + 1] = bB; }
        __syncthreads();

        // ---- Phase B: 8 slots x 2 rows x 32 cols; u reads are wave-uniform (broadcast) ----
        #pragma unroll
        for (int j = 0; j < 8; ++j) {
            const int e = 8 * eh + j;
            const float* Ue = &Ul[e][32 * cq];
            float a0 = 0.f, a1 = 0.f;
            #pragma unroll
            for (int k = 0; k < 8; ++k) {
                const float4 u = *reinterpret_cast<const float4*>(Ue + 4 * k);
                a0 = fmaf(pA[k].x, u.x, a0); a0 = fmaf(pA[k].y, u.y, a0);
                a0 = fmaf(pA[k].z, u.z, a0); a0 = fmaf(pA[k].w, u.w, a0);
                a1 = fmaf(pB[k].x, u.x, a1); a1 = fmaf(pB[k].y, u.y, a1);
                a1 = fmaf(pB[k].z, u.z, a1); a1 = fmaf(pB[k].w, u.w, a1);
            }
            part4[cq][e][wl]      = a0;   // [cq][..] layout: stride-4B lanes, conflict-free
            part4[cq][e][wl + 64] = a1;
        }
        __syncthreads();

        // ---- finalize: wave w scores slots 2w, 2w+1 (deterministic quarter order) ----
        #pragma unroll
        for (int s2 = 0; s2 < 2; ++s2) {
            const int e = 2 * w + s2;
            const float p0 = ((part4[0][e][wl] + part4[1][e][wl])
                            + (part4[2][e][wl] + part4[3][e][wl]));
            const float p1 = ((part4[0][e][wl + 64] + part4[1][e][wl + 64])
                            + (part4[2][e][wl + 64] + part4[3][e][wl + 64]));
            const float d0 = p0 + Rl[e][wl];
            const float d1 = p1 + Rl[e][wl + 64];
            float s = fmaf(d0, d0, d1 * d1);
            #pragma unroll
            for (int m = 1; m < 64; m <<= 1) s += __shfl_xor(s, m);
            if (wl == 0) {
                const int bb = El[e];
                if (bb >= 0) out[bb] = -s;
            }
        }
        __syncthreads();   // Ul/Rl/El/part4 free before next chunk
    }
}

extern "C" void kernel_launch(void* const* d_in, const int* in_sizes, int n_in,
                              void* d_out, int out_size, void* d_ws, size_t ws_size,
                              hipStream_t stream) {
    const float* head = (const float*)d_in[0];
    const float* tail = (const float*)d_in[1];
    const float* edge = (const float*)d_in[2];
    const float* proj = (const float*)d_in[3];
    const int*   idx  = (const int*)d_in[4];
    float* out = (float*)d_out;

    const int B    = in_sizes[0] / D;          // 16384
    const int nrel = in_sizes[3] / (D * D);    // 1000

    transr_fused<<<nrel, 512, 0, stream>>>(head, tail, edge, proj, idx, out, B);
}